// Round 3
// baseline (194.033 us; speedup 1.0000x reference)
//
#include <hip/hip_runtime.h>

// ---------------------------------------------------------------------------
// GAT (2-layer, dense mask) on gfx950 — R17.
// R16 post-mortem: bundled {xA frag-pack, wave-per-row gemm2} regressed +11us
// (gemm2 shuffle-serialization suspected). Reverted both.
// R17 = R15 base + ONE change: k_att1 global-direct. Evidence: k_att2 has the
// identical inner math, reads B global-direct with zero barriers, never shows
// in top-5; att1's 16x {global_load_lds stage -> vmcnt(0) drain -> s_barrier}
// is the m97-style barrier stall at 8 blocks/CU with MfmaUtil ~7%. whB (4 MB)
// is aggregate-L2-resident; per-(h,split) slice 128 KB re-read by 64 blocks is
// L2-served (~256 MB @ 34.5 TB/s ~ 7us). Barrier-free lets the compiler
// software-pipeline loads across independent c-iterations.
// ---------------------------------------------------------------------------

typedef _Float16 h2 __attribute__((ext_vector_type(2)));
typedef _Float16 half8 __attribute__((ext_vector_type(8)));
typedef __attribute__((ext_vector_type(4))) float f32x4;
typedef unsigned long long u64;
typedef unsigned short u16;
typedef unsigned int u32;

__device__ __forceinline__ u16 f2h(float f){
  union { _Float16 h; u16 u; } c; c.h = (_Float16)f; return c.u;
}
__device__ __forceinline__ h2 u2h2(u32 u){ union { u32 u; h2 h; } c; c.u = u; return c.h; }
__device__ __forceinline__ u32 h22u(h2 h){ union { u32 u; h2 h; } c; c.h = h; return c.u; }
__device__ __forceinline__ half8 pk2h8(uint4 v){ union { uint4 u; half8 h; } c; c.u = v; return c.h; }

// ===== K0: pack W f32 -> f16 B-layout [h][fgb(64)][o(64)][q(8)] ============
__global__ __launch_bounds__(256) void k_wpack(const float* __restrict__ W,
                                               u16* __restrict__ Wb16){
  int t = blockIdx.x * 256 + threadIdx.x;   // 0..32767 = 8 h x 64 fgb x 64 o
  int o   = t & 63;
  int fgb = (t >> 6) & 63;
  int h   = t >> 12;
  const float* src = W + ((size_t)h * 512 + fgb * 8) * 64 + o;
  u32 pk[4];
  #pragma unroll
  for (int p = 0; p < 4; ++p)
    pk[p] = (u32)f2h(src[(2 * p) * 64]) | ((u32)f2h(src[(2 * p + 1) * 64]) << 16);
  *(uint4*)(Wb16 + ((size_t)h * 4096 + fgb * 64 + o) * 8) = *(uint4*)pk;
}

// ===== K1: Wh = x @ W[h] (B-frags from global Wb16) + tables + whB,        =
// =====     plus block-specialized adj bitmask pack (bx >= 64)              =
__global__ __launch_bounds__(256) void k_gemm1(const float* __restrict__ x,
                                               const u16* __restrict__ Wb16,
                                               const float* __restrict__ av,
                                               const int* __restrict__ adj,
                                               u16* __restrict__ whB,
                                               u64* __restrict__ bits_t,
                                               float* __restrict__ r1,
                                               u16* __restrict__ e21h, u16* __restrict__ e202h){
  __shared__ u16 tr[4096];                 // 8 KB transpose buffer (only LDS)
  int h    = blockIdx.y;
  int bx   = blockIdx.x;
  int tid  = threadIdx.x;
  int lane = tid & 63;
  int wv   = tid >> 6;

  if (bx >= 64){
    // ---- adj-pack slice (transposed bitmask; independent of gemm) ----
    int B = h * 64 + (bx - 64);            // 0..511
    int uid0 = B * 512 + wv * 128;
    for (int k = 0; k < 128; k += 8){
      int v[8];
      #pragma unroll
      for (int q = 0; q < 8; ++q){
        int uid = uid0 + k + q;
        v[q] = adj[(size_t)(uid >> 6) * 4096 + ((uid & 63) << 6) + lane];
      }
      u64 m[8];
      #pragma unroll
      for (int q = 0; q < 8; ++q) m[q] = __ballot(v[q] != 0);
      if (lane == 0){
        #pragma unroll
        for (int q = 0; q < 8; ++q){
          int uid = uid0 + k + q;
          bits_t[(size_t)(uid & 63) * 4096 + (uid >> 6)] = m[q];
        }
      }
    }
    return;
  }

  // ---- gemm path ----
  int row16 = lane & 15, grp = lane >> 4;
  int n0 = bx * 64;
  int n0w = n0 + wv * 16;
  const u16* wb = Wb16 + (size_t)h * 32768;

  f32x4 acc[4] = {};
  #pragma unroll 4
  for (int ks = 0; ks < 16; ++ks){
    int fgb = ks * 4 + grp;
    const float* xs = x + (size_t)(n0w + row16) * 512 + fgb * 8;
    float4 xv0 = ((const float4*)xs)[0];
    float4 xv1 = ((const float4*)xs)[1];
    u32 ax[4];
    ax[0] = (u32)f2h(xv0.x) | ((u32)f2h(xv0.y) << 16);
    ax[1] = (u32)f2h(xv0.z) | ((u32)f2h(xv0.w) << 16);
    ax[2] = (u32)f2h(xv1.x) | ((u32)f2h(xv1.y) << 16);
    ax[3] = (u32)f2h(xv1.z) | ((u32)f2h(xv1.w) << 16);
    half8 af = pk2h8(*(uint4*)ax);
    #pragma unroll
    for (int nt = 0; nt < 4; ++nt){
      half8 bf = *(const half8*)(wb + ((size_t)fgb * 64 + nt * 16 + row16) * 8);
      acc[nt] = __builtin_amdgcn_mfma_f32_16x16x32_f16(af, bf, acc[nt], 0, 0, 0);
    }
  }
  // ---- scale-free score tables ----
  float a1v[4], a2v[4];
  #pragma unroll
  for (int nt = 0; nt < 4; ++nt){
    a1v[nt] = av[h * 128 + nt * 16 + row16];
    a2v[nt] = av[h * 128 + 64 + nt * 16 + row16];
  }
  #pragma unroll
  for (int r = 0; r < 4; ++r){
    float p1 = acc[0][r]*a1v[0] + acc[1][r]*a1v[1] + acc[2][r]*a1v[2] + acc[3][r]*a1v[3];
    float p2 = acc[0][r]*a2v[0] + acc[1][r]*a2v[1] + acc[2][r]*a2v[2] + acc[3][r]*a2v[3];
    #pragma unroll
    for (int d = 1; d < 16; d <<= 1){ p1 += __shfl_xor(p1, d, 64); p2 += __shfl_xor(p2, d, 64); }
    if (row16 == 0){
      int idx = h * 4096 + n0w + grp * 4 + r;
      r1[idx]    = __expf(-0.8f * p1);     // row scale e^{-0.8 s1}
      e21h[idx]  = f2h(__expf(p2));
      e202h[idx] = f2h(__expf(0.2f * p2));
    }
  }
  // ---- whB f16 pack via LDS transpose ----
  #pragma unroll
  for (int nt = 0; nt < 4; ++nt)
    #pragma unroll
    for (int r = 0; r < 4; ++r){
      int jl = wv * 16 + grp * 4 + r;
      int o  = nt * 16 + row16;
      tr[((jl >> 3) * 64 + o) * 8 + (jl & 7)] = f2h(acc[nt][r]);
    }
  __syncthreads();
  u16* dst = whB + (size_t)h * 262144 + (size_t)n0 * 64;
  #pragma unroll
  for (int q = 0; q < 2; ++q)
    *(uint4*)(dst + (tid * 2 + q) * 8) = *(const uint4*)(tr + (tid * 2 + q) * 8);
}

// ===== K2: layer-1 attention — global-direct, barrier-free =================
__global__ __launch_bounds__(256) void k_att1(const u16* __restrict__ whB,
                                              const u64* __restrict__ bits_t,
                                              const float* __restrict__ r1,
                                              const u16* __restrict__ e21h, const u16* __restrict__ e202h,
                                              u16* __restrict__ pnum, float* __restrict__ pden){
  __shared__ u32 smLut[4];
  int h     = blockIdx.y;
  int iblk  = blockIdx.x;
  int split = blockIdx.z;
  int lane = threadIdx.x & 63;
  int wv   = threadIdx.x >> 6;
  int row16 = lane & 15, grp = lane >> 4;
  if (threadIdx.x < 4)
    smLut[threadIdx.x] = ((threadIdx.x & 1) ? 0xFFFFu : 0u) | ((threadIdx.x & 2) ? 0xFFFF0000u : 0u);
  __syncthreads();                         // only barrier in the kernel
  int i = iblk * 64 + wv * 16 + row16;
  int hoff = h * 4096;
  u32 rb = (u32)f2h(r1[hoff + i]); rb |= rb << 16;
  h2 rr = u2h2(rb);
  const u16* whBh = whB + (size_t)h * 262144;
  int jbeg = split * 1024;

  half8 bden;                              // ones-column B frag for den
  {
    u32 z[4] = {0,0,0,0};
    if (row16 == 0){ z[0]=0x3C003C00u; z[1]=0x3C003C00u; z[2]=0x3C003C00u; z[3]=0x3C003C00u; }
    bden = pk2h8(*(uint4*)z);
  }

  f32x4 acc[4] = {};
  f32x4 accden = {};
  for (int c = 0; c < 16; ++c){
    int j0 = jbeg + c * 64;
    u64 mrow = bits_t[(size_t)(split * 16 + c) * 4096 + i];   // coalesced
    #pragma unroll
    for (int ks = 0; ks < 2; ++ks){
      uint4 e1q = *(const uint4*)(e21h  + hoff + j0 + ks * 32 + grp * 8);
      uint4 e2q = *(const uint4*)(e202h + hoff + j0 + ks * 32 + grp * 8);
      u32 es[4] = {e1q.x, e1q.y, e1q.z, e1q.w};
      u32 gs[4] = {e2q.x, e2q.y, e2q.z, e2q.w};
      int sb = (j0 >> 3) + ks * 4 + grp;           // [j/8][o][j&7] block
      const u16* bbase = whBh + (size_t)sb * 512;
      half8 bf0 = *(const half8*)(bbase + (0 * 16 + row16) * 8);
      half8 bf1 = *(const half8*)(bbase + (1 * 16 + row16) * 8);
      half8 bf2 = *(const half8*)(bbase + (2 * 16 + row16) * 8);
      half8 bf3 = *(const half8*)(bbase + (3 * 16 + row16) * 8);
      u32 mb = ((u32)(mrow >> (ks * 32)) >> (grp * 8)) & 0xffu;
      u32 pk[4];
      #pragma unroll
      for (int t2i = 0; t2i < 4; ++t2i){
        h2 w = __builtin_elementwise_max(u2h2(es[t2i]), rr * u2h2(gs[t2i]));
        pk[t2i] = h22u(w) & smLut[(mb >> (2 * t2i)) & 3u];
      }
      half8 af = pk2h8(*(uint4*)pk);
      acc[0] = __builtin_amdgcn_mfma_f32_16x16x32_f16(af, bf0, acc[0], 0, 0, 0);
      acc[1] = __builtin_amdgcn_mfma_f32_16x16x32_f16(af, bf1, acc[1], 0, 0, 0);
      acc[2] = __builtin_amdgcn_mfma_f32_16x16x32_f16(af, bf2, acc[2], 0, 0, 0);
      acc[3] = __builtin_amdgcn_mfma_f32_16x16x32_f16(af, bf3, acc[3], 0, 0, 0);
      accden = __builtin_amdgcn_mfma_f32_16x16x32_f16(af, bden, accden, 0, 0, 0);
    }
  }

  #pragma unroll
  for (int r4 = 0; r4 < 4; ++r4){
    int n = iblk * 64 + wv * 16 + grp * 4 + r4;
    if (row16 == 0)
      pden[((size_t)split * 8 + h) * 4096 + n] = accden[r4];
    u16* dst = pnum + ((size_t)split * 4096 + n) * 512 + h * 64 + row16;
    #pragma unroll
    for (int nt = 0; nt < 4; ++nt)
      dst[nt * 16] = f2h(acc[nt][r4]);
  }
}

// ===== K3: combine + Who = h @ Wout + layer-2 tables (R14 version) =========
__global__ __launch_bounds__(256) void k_gemm2(const u16* __restrict__ pnum,
                                               const float* __restrict__ pden,
                                               const float* __restrict__ Wout,
                                               const float* __restrict__ aout,
                                               u16* __restrict__ whoB,
                                               float* __restrict__ r1o,
                                               u16* __restrict__ e21oh, u16* __restrict__ e202oh){
  __shared__ float Wl[8192];                  // 512 x 16
  __shared__ float hrow[16 * 516];            // combined+elu rows, padded stride
  __shared__ float sden[128];                 // den[h][n]
  int n0 = blockIdx.x * 16;
  for (int t = threadIdx.x; t < 8192; t += 256) Wl[t] = Wout[t];
  if (threadIdx.x < 128){
    int hh = threadIdx.x >> 4, nn = threadIdx.x & 15;
    float d = 0.f;
    #pragma unroll
    for (int s = 0; s < 4; ++s) d += pden[((size_t)s * 8 + hh) * 4096 + n0 + nn];
    sden[threadIdx.x] = d;
  }
  __syncthreads();
  {
    int nn = threadIdx.x >> 4;
    int fc = threadIdx.x & 15;
    int f0 = fc * 32;
    int hh = fc >> 1;
    float dinv = 1.f / sden[hh * 16 + nn];
    float v[32];
    #pragma unroll
    for (int k = 0; k < 32; ++k) v[k] = 0.f;
    #pragma unroll
    for (int s = 0; s < 4; ++s){
      const u16* p = pnum + ((size_t)s * 4096 + n0 + nn) * 512 + f0;
      #pragma unroll
      for (int q = 0; q < 4; ++q){
        uint4 raw = *(const uint4*)(p + q * 8);
        u32 rw[4] = {raw.x, raw.y, raw.z, raw.w};
        #pragma unroll
        for (int d2 = 0; d2 < 4; ++d2){
          h2 dh = u2h2(rw[d2]);
          v[q * 8 + d2 * 2]     += (float)dh.x;
          v[q * 8 + d2 * 2 + 1] += (float)dh.y;
        }
      }
    }
    #pragma unroll
    for (int k = 0; k < 32; ++k){
      float val = v[k] * dinv;
      val = val > 0.f ? val : (__expf(val) - 1.f);
      hrow[nn * 516 + f0 + k] = val;
    }
  }
  __syncthreads();
  int c  = threadIdx.x & 15;
  int rl = threadIdx.x >> 4;
  int n = n0 + rl;
  const float4* hr = (const float4*)(hrow + rl * 516);
  float acc = 0.f;
  #pragma unroll 8
  for (int f4 = 0; f4 < 128; ++f4){
    float4 hv = hr[f4];
    int f = f4 * 4;
    acc += hv.x * Wl[f * 16 + c] + hv.y * Wl[(f + 1) * 16 + c]
         + hv.z * Wl[(f + 2) * 16 + c] + hv.w * Wl[(f + 3) * 16 + c];
  }
  whoB[((size_t)(n >> 3) * 16 + c) * 8 + (n & 7)] = f2h(acc);
  float p1 = acc * aout[c], p2 = acc * aout[16 + c];
  #pragma unroll
  for (int d = 1; d < 16; d <<= 1){ p1 += __shfl_xor(p1, d, 64); p2 += __shfl_xor(p2, d, 64); }
  if (c == 0){
    r1o[n]    = __expf(-0.8f * p1);
    e21oh[n]  = f2h(__expf(p2));
    e202oh[n] = f2h(__expf(0.2f * p2));
  }
}

// ===== K4: layer-2 attention (16-way split, f16, global-direct) ============
__global__ __launch_bounds__(256) void k_att2(const u16* __restrict__ whoB,
                                              const u64* __restrict__ bits_t,
                                              const float* __restrict__ r1o,
                                              const u16* __restrict__ e21oh, const u16* __restrict__ e202oh,
                                              float* __restrict__ pnum, float* __restrict__ pden){
  __shared__ u32 smLut[4];
  int iblk  = blockIdx.x;
  int split = blockIdx.y;                     // 0..15
  int lane = threadIdx.x & 63;
  int wv   = threadIdx.x >> 6;
  int row16 = lane & 15, grp = lane >> 4;
  if (threadIdx.x < 4)
    smLut[threadIdx.x] = ((threadIdx.x & 1) ? 0xFFFFu : 0u) | ((threadIdx.x & 2) ? 0xFFFF0000u : 0u);
  __syncthreads();
  int i = iblk * 64 + wv * 16 + row16;
  u32 rb = (u32)f2h(r1o[i]); rb |= rb << 16;
  h2 rr = u2h2(rb);
  int jbeg = split * 256;
  half8 bden;
  {
    u32 z[4] = {0,0,0,0};
    if (row16 == 0){ z[0]=0x3C003C00u; z[1]=0x3C003C00u; z[2]=0x3C003C00u; z[3]=0x3C003C00u; }
    bden = pk2h8(*(uint4*)z);
  }

  f32x4 acc = {};
  f32x4 accden = {};
  #pragma unroll
  for (int c = 0; c < 4; ++c){
    int j0 = jbeg + c * 64;
    u64 mrow = bits_t[(size_t)(split * 4 + c) * 4096 + i];   // coalesced
    #pragma unroll
    for (int ks = 0; ks < 2; ++ks){
      int sb = (j0 >> 3) + ks * 4 + grp;
      half8 bf = *(const half8*)(whoB + ((size_t)sb * 16 + row16) * 8);
      uint4 e1q = *(const uint4*)(e21oh  + j0 + ks * 32 + grp * 8);
      uint4 e2q = *(const uint4*)(e202oh + j0 + ks * 32 + grp * 8);
      u32 es[4] = {e1q.x, e1q.y, e1q.z, e1q.w};
      u32 gs[4] = {e2q.x, e2q.y, e2q.z, e2q.w};
      u32 mb = ((u32)(mrow >> (ks * 32)) >> (grp * 8)) & 0xffu;
      u32 pk[4];
      #pragma unroll
      for (int t2i = 0; t2i < 4; ++t2i){
        h2 w = __builtin_elementwise_max(u2h2(es[t2i]), rr * u2h2(gs[t2i]));
        pk[t2i] = h22u(w) & smLut[(mb >> (2 * t2i)) & 3u];
      }
      half8 af = pk2h8(*(uint4*)pk);
      acc    = __builtin_amdgcn_mfma_f32_16x16x32_f16(af, bf, acc, 0, 0, 0);
      accden = __builtin_amdgcn_mfma_f32_16x16x32_f16(af, bden, accden, 0, 0, 0);
    }
  }
  #pragma unroll
  for (int r4 = 0; r4 < 4; ++r4){
    int n = iblk * 64 + wv * 16 + grp * 4 + r4;
    if (row16 == 0)
      pden[(size_t)n * 16 + split] = accden[r4];
    pnum[((size_t)n * 16 + split) * 16 + row16] = acc[r4];
  }
}

// ===== K5: combine + elu + log_softmax =====================================
__global__ __launch_bounds__(256) void k_final(const float* __restrict__ pnum,
                                               const float* __restrict__ pden,
                                               float* __restrict__ out){
  int tid = blockIdx.x * 256 + threadIdx.x;   // 65536
  int c = tid & 15;
  int n = tid >> 4;
  float num = 0.f, den = 0.f;
  #pragma unroll
  for (int s = 0; s < 16; ++s){
    num += pnum[((size_t)n * 16 + s) * 16 + c];
    den += pden[(size_t)n * 16 + s];
  }
  float v = num / den;
  v = v > 0.f ? v : (__expf(v) - 1.f);
  float m = v;
  #pragma unroll
  for (int d = 1; d < 16; d <<= 1) m = fmaxf(m, __shfl_xor(m, d, 64));
  float es = __expf(v - m), ss = es;
  #pragma unroll
  for (int d = 1; d < 16; d <<= 1) ss += __shfl_xor(ss, d, 64);
  out[(size_t)n * 16 + c] = v - m - __logf(ss);
}

// ---------------------------------------------------------------------------
extern "C" void kernel_launch(void* const* d_in, const int* in_sizes, int n_in,
                              void* d_out, int out_size, void* d_ws, size_t ws_size,
                              hipStream_t stream){
  (void)in_sizes; (void)n_in; (void)out_size; (void)ws_size;
  const float* x    = (const float*)d_in[0];
  const int*   adj  = (const int*)d_in[1];
  const float* W    = (const float*)d_in[2];
  const float* av   = (const float*)d_in[3];
  const float* Wout = (const float*)d_in[4];
  const float* aout = (const float*)d_in[5];
  float* out = (float*)d_out;
  char* ws = (char*)d_ws;

  u64*  bits_t  = (u64*)(ws + 0x0000000);        // 2 MB [64][4096]
  u16*  whB     = (u16*)(ws + 0x0200000);        // 4 MB f16 [8][j/8][o][8]
  float* r1     = (float*)(ws + 0x0600000);      // 128 KB
  u16*  e21h    = (u16*)(ws + 0x0620000);        // 64 KB f16
  u16*  e202h   = (u16*)(ws + 0x0630000);        // 64 KB f16
  u16*  pnum1   = (u16*)(ws + 0x0680000);        // 16 MB f16 [4][4096][512]
  float* pden1  = (float*)(ws + 0x1680000);      // 512 KB [4][8][4096]
  u16*  whoB    = (u16*)(ws + 0x1700000);        // 128 KB f16
  float* r1o    = (float*)(ws + 0x1720000);      // 16 KB
  u16*  e21oh   = (u16*)(ws + 0x1724000);        // 8 KB f16
  u16*  e202oh  = (u16*)(ws + 0x1726000);        // 8 KB f16
  float* pnum2  = (float*)(ws + 0x1730000);      // 4 MB [4096][16][16]
  float* pden2  = (float*)(ws + 0x1B30000);      // 256 KB
  // Wb16 aliases pnum2's region: written by k_wpack, consumed by k_gemm1,
  // then dead before k_att2 overwrites the region (stream-ordered safe).
  u16*  Wb16    = (u16*)(ws + 0x1730000);        // 512 KB f16 [8][64][64][8]

  k_wpack<<<dim3(128), dim3(256), 0, stream>>>(W, Wb16);
  k_gemm1<<<dim3(128, 8), dim3(256), 0, stream>>>(x, Wb16, av, adj, whB, bits_t, r1, e21h, e202h);
  k_att1<<<dim3(64, 8, 4), dim3(256), 0, stream>>>(whB, bits_t, r1, e21h, e202h, pnum1, pden1);
  k_gemm2<<<dim3(256), dim3(256), 0, stream>>>(pnum1, pden1, Wout, aout, whoB, r1o, e21oh, e202oh);
  k_att2<<<dim3(64, 16), dim3(256), 0, stream>>>(whoB, bits_t, r1o, e21oh, e202oh, pnum2, pden2);
  k_final<<<dim3(256), dim3(256), 0, stream>>>(pnum2, pden2, out);
}

// Round 4
// 177.981 us; speedup vs baseline: 1.0902x; 1.0902x over previous
//
#include <hip/hip_runtime.h>

// ---------------------------------------------------------------------------
// GAT (2-layer, dense mask) on gfx950 — R18.
// R17 post-mortem: global-direct att1 = 61us (L2-latency-bound, MfmaUtil 14%)
// vs <=41 staged -> LDS dbuf restored. R14 (serial gemm+adj = 43) vs R15
// (parallel = 41): serial sum ~ parallel max => ONE phase is ~40us alone.
// Gemm half is insensitive to 4x occupancy change and has ~1us of MFMA ->
// suspect adj-pack: 128 scalar dword loads/wave + 262K single-lane 8B stores.
// R18 = R15 base + int4 adj-pack: 16B/lane loads (4x fewer load instrs),
// nibble + 4-step shfl_xor OR-reduce per 16-lane group, 4 concurrent stores.
// ---------------------------------------------------------------------------

typedef _Float16 h2 __attribute__((ext_vector_type(2)));
typedef _Float16 half8 __attribute__((ext_vector_type(8)));
typedef __attribute__((ext_vector_type(4))) float f32x4;
typedef unsigned long long u64;
typedef unsigned short u16;
typedef unsigned int u32;

__device__ __forceinline__ u16 f2h(float f){
  union { _Float16 h; u16 u; } c; c.h = (_Float16)f; return c.u;
}
__device__ __forceinline__ h2 u2h2(u32 u){ union { u32 u; h2 h; } c; c.u = u; return c.h; }
__device__ __forceinline__ u32 h22u(h2 h){ union { u32 u; h2 h; } c; c.h = h; return c.u; }
__device__ __forceinline__ half8 pk2h8(uint4 v){ union { uint4 u; half8 h; } c; c.u = v; return c.h; }

__device__ __forceinline__ void async16(void* lds, const void* g){
  __builtin_amdgcn_global_load_lds((const __attribute__((address_space(1))) u32*)g,
                                   (__attribute__((address_space(3))) u32*)lds, 16, 0, 0);
}
__device__ __forceinline__ void async4(void* lds, const void* g){
  __builtin_amdgcn_global_load_lds((const __attribute__((address_space(1))) u32*)g,
                                   (__attribute__((address_space(3))) u32*)lds, 4, 0, 0);
}

// ===== K0: pack W f32 -> f16 B-layout [h][fgb(64)][o(64)][q(8)] ============
__global__ __launch_bounds__(256) void k_wpack(const float* __restrict__ W,
                                               u16* __restrict__ Wb16){
  int t = blockIdx.x * 256 + threadIdx.x;   // 0..32767 = 8 h x 64 fgb x 64 o
  int o   = t & 63;
  int fgb = (t >> 6) & 63;
  int h   = t >> 12;
  const float* src = W + ((size_t)h * 512 + fgb * 8) * 64 + o;
  u32 pk[4];
  #pragma unroll
  for (int p = 0; p < 4; ++p)
    pk[p] = (u32)f2h(src[(2 * p) * 64]) | ((u32)f2h(src[(2 * p + 1) * 64]) << 16);
  *(uint4*)(Wb16 + ((size_t)h * 4096 + fgb * 64 + o) * 8) = *(uint4*)pk;
}

// ===== K1: Wh = x @ W[h] (B-frags from global Wb16) + tables + whB,        =
// =====     plus block-specialized int4 adj bitmask pack (bx >= 64)         =
__global__ __launch_bounds__(256) void k_gemm1(const float* __restrict__ x,
                                               const u16* __restrict__ Wb16,
                                               const float* __restrict__ av,
                                               const int* __restrict__ adj,
                                               u16* __restrict__ whB,
                                               u64* __restrict__ bits_t,
                                               float* __restrict__ r1,
                                               u16* __restrict__ e21h, u16* __restrict__ e202h){
  __shared__ u16 tr[4096];                 // 8 KB transpose buffer (only LDS)
  int h    = blockIdx.y;
  int bx   = blockIdx.x;
  int tid  = threadIdx.x;
  int lane = tid & 63;
  int wv   = tid >> 6;

  if (bx >= 64){
    // ---- int4 adj-pack: wave handles 2 full rows of adj ----
    int B  = h * 64 + (bx - 64);           // 0..511
    int r0 = B * 8 + wv * 2;
    #pragma unroll
    for (int rr2 = 0; rr2 < 2; ++rr2){
      int r = r0 + rr2;
      const int4* rowp = (const int4*)(adj + (size_t)r * 4096);
      #pragma unroll 4
      for (int g = 0; g < 16; ++g){
        int4 v = rowp[g * 64 + lane];      // 1 KB per wave-load, coalesced
        u32 nib = (v.x != 0 ? 1u : 0u) | (v.y != 0 ? 2u : 0u)
                | (v.z != 0 ? 4u : 0u) | (v.w != 0 ? 8u : 0u);
        u64 m = (u64)nib << (4 * (lane & 15));
        m |= __shfl_xor(m, 1, 64);
        m |= __shfl_xor(m, 2, 64);
        m |= __shfl_xor(m, 4, 64);
        m |= __shfl_xor(m, 8, 64);
        if ((lane & 15) == 0){
          int cc = g * 4 + (lane >> 4);
          bits_t[(size_t)cc * 4096 + r] = m;
        }
      }
    }
    return;
  }

  // ---- gemm path ----
  int row16 = lane & 15, grp = lane >> 4;
  int n0 = bx * 64;
  int n0w = n0 + wv * 16;
  const u16* wb = Wb16 + (size_t)h * 32768;

  f32x4 acc[4] = {};
  #pragma unroll 4
  for (int ks = 0; ks < 16; ++ks){
    int fgb = ks * 4 + grp;
    const float* xs = x + (size_t)(n0w + row16) * 512 + fgb * 8;
    float4 xv0 = ((const float4*)xs)[0];
    float4 xv1 = ((const float4*)xs)[1];
    u32 ax[4];
    ax[0] = (u32)f2h(xv0.x) | ((u32)f2h(xv0.y) << 16);
    ax[1] = (u32)f2h(xv0.z) | ((u32)f2h(xv0.w) << 16);
    ax[2] = (u32)f2h(xv1.x) | ((u32)f2h(xv1.y) << 16);
    ax[3] = (u32)f2h(xv1.z) | ((u32)f2h(xv1.w) << 16);
    half8 af = pk2h8(*(uint4*)ax);
    #pragma unroll
    for (int nt = 0; nt < 4; ++nt){
      half8 bf = *(const half8*)(wb + ((size_t)fgb * 64 + nt * 16 + row16) * 8);
      acc[nt] = __builtin_amdgcn_mfma_f32_16x16x32_f16(af, bf, acc[nt], 0, 0, 0);
    }
  }
  // ---- scale-free score tables ----
  float a1v[4], a2v[4];
  #pragma unroll
  for (int nt = 0; nt < 4; ++nt){
    a1v[nt] = av[h * 128 + nt * 16 + row16];
    a2v[nt] = av[h * 128 + 64 + nt * 16 + row16];
  }
  #pragma unroll
  for (int r = 0; r < 4; ++r){
    float p1 = acc[0][r]*a1v[0] + acc[1][r]*a1v[1] + acc[2][r]*a1v[2] + acc[3][r]*a1v[3];
    float p2 = acc[0][r]*a2v[0] + acc[1][r]*a2v[1] + acc[2][r]*a2v[2] + acc[3][r]*a2v[3];
    #pragma unroll
    for (int d = 1; d < 16; d <<= 1){ p1 += __shfl_xor(p1, d, 64); p2 += __shfl_xor(p2, d, 64); }
    if (row16 == 0){
      int idx = h * 4096 + n0w + grp * 4 + r;
      r1[idx]    = __expf(-0.8f * p1);     // row scale e^{-0.8 s1}
      e21h[idx]  = f2h(__expf(p2));
      e202h[idx] = f2h(__expf(0.2f * p2));
    }
  }
  // ---- whB f16 pack via LDS transpose ----
  #pragma unroll
  for (int nt = 0; nt < 4; ++nt)
    #pragma unroll
    for (int r = 0; r < 4; ++r){
      int jl = wv * 16 + grp * 4 + r;
      int o  = nt * 16 + row16;
      tr[((jl >> 3) * 64 + o) * 8 + (jl & 7)] = f2h(acc[nt][r]);
    }
  __syncthreads();
  u16* dst = whB + (size_t)h * 262144 + (size_t)n0 * 64;
  #pragma unroll
  for (int q = 0; q < 2; ++q)
    *(uint4*)(dst + (tid * 2 + q) * 8) = *(const uint4*)(tr + (tid * 2 + q) * 8);
}

// ===== K2: layer-1 attention (LDS dbuf, f16 + packed w-gen) ================
__global__ __launch_bounds__(256) void k_att1(const u16* __restrict__ whB,
                                              const u64* __restrict__ bits_t,
                                              const float* __restrict__ r1,
                                              const u16* __restrict__ e21h, const u16* __restrict__ e202h,
                                              u16* __restrict__ pnum, float* __restrict__ pden){
  __shared__ u16  smB[2][4096];            // 64 j x 64 o f16, [j/8][o][j&7]
  __shared__ u32  smT[2][2][64];           // staged f16 tables
  __shared__ u32  smLut[4];
  int h     = blockIdx.y;
  int iblk  = blockIdx.x;
  int split = blockIdx.z;
  int lane = threadIdx.x & 63;
  int wv   = threadIdx.x >> 6;
  int row16 = lane & 15, grp = lane >> 4;
  if (threadIdx.x < 4)
    smLut[threadIdx.x] = ((threadIdx.x & 1) ? 0xFFFFu : 0u) | ((threadIdx.x & 2) ? 0xFFFF0000u : 0u);
  int i = iblk * 64 + wv * 16 + row16;
  int hoff = h * 4096;
  u32 rb = (u32)f2h(r1[hoff + i]); rb |= rb << 16;
  h2 rr = u2h2(rb);
  const u16* whBh = whB + (size_t)h * 262144;
  int jbeg = split * 1024;

  half8 bden;                              // ones-column B frag for den
  {
    u32 z[4] = {0,0,0,0};
    if (row16 == 0){ z[0]=0x3C003C00u; z[1]=0x3C003C00u; z[2]=0x3C003C00u; z[3]=0x3C003C00u; }
    bden = pk2h8(*(uint4*)z);
  }

  auto stage = [&](int bb, int j0){
    const char* g = (const char*)whBh + (size_t)j0 * 128 + wv * 2048 + lane * 16;
    char* l = (char*)(&smB[bb][0]) + wv * 2048;
    async16(l, g);
    async16(l + 1024, g + 1024);
    if (wv == 0)      async4(&smT[bb][0][0], (const char*)(e21h  + hoff + j0) + lane * 4);
    else if (wv == 1) async4(&smT[bb][1][0], (const char*)(e202h + hoff + j0) + lane * 4);
  };

  f32x4 acc[4] = {};
  f32x4 accden = {};
  stage(0, jbeg);
  for (int c = 0; c < 16; ++c){
    int bb = c & 1;
    u64 mrow = bits_t[(size_t)(split * 16 + c) * 4096 + i];   // coalesced
    __syncthreads();                       // buf bb staged; buf bb^1 free
    if (c < 15) stage(bb ^ 1, jbeg + (c + 1) * 64);
    #pragma unroll
    for (int ks = 0; ks < 2; ++ks){
      uint4 e1q = *(const uint4*)((const char*)&smT[bb][0][0] + ks * 64 + grp * 16);
      uint4 e2q = *(const uint4*)((const char*)&smT[bb][1][0] + ks * 64 + grp * 16);
      u32 es[4] = {e1q.x, e1q.y, e1q.z, e1q.w};
      u32 gs[4] = {e2q.x, e2q.y, e2q.z, e2q.w};
      const u16* bbase = &smB[bb][(ks * 4 + grp) * 512];
      half8 bf0 = *(const half8*)(bbase + (0 * 16 + row16) * 8);
      half8 bf1 = *(const half8*)(bbase + (1 * 16 + row16) * 8);
      half8 bf2 = *(const half8*)(bbase + (2 * 16 + row16) * 8);
      half8 bf3 = *(const half8*)(bbase + (3 * 16 + row16) * 8);
      u32 mb = ((u32)(mrow >> (ks * 32)) >> (grp * 8)) & 0xffu;
      u32 pk[4];
      #pragma unroll
      for (int t2i = 0; t2i < 4; ++t2i){
        h2 w = __builtin_elementwise_max(u2h2(es[t2i]), rr * u2h2(gs[t2i]));
        pk[t2i] = h22u(w) & smLut[(mb >> (2 * t2i)) & 3u];
      }
      half8 af = pk2h8(*(uint4*)pk);
      acc[0] = __builtin_amdgcn_mfma_f32_16x16x32_f16(af, bf0, acc[0], 0, 0, 0);
      acc[1] = __builtin_amdgcn_mfma_f32_16x16x32_f16(af, bf1, acc[1], 0, 0, 0);
      acc[2] = __builtin_amdgcn_mfma_f32_16x16x32_f16(af, bf2, acc[2], 0, 0, 0);
      acc[3] = __builtin_amdgcn_mfma_f32_16x16x32_f16(af, bf3, acc[3], 0, 0, 0);
      accden = __builtin_amdgcn_mfma_f32_16x16x32_f16(af, bden, accden, 0, 0, 0);
    }
  }

  #pragma unroll
  for (int r4 = 0; r4 < 4; ++r4){
    int n = iblk * 64 + wv * 16 + grp * 4 + r4;
    if (row16 == 0)
      pden[((size_t)split * 8 + h) * 4096 + n] = accden[r4];
    u16* dst = pnum + ((size_t)split * 4096 + n) * 512 + h * 64 + row16;
    #pragma unroll
    for (int nt = 0; nt < 4; ++nt)
      dst[nt * 16] = f2h(acc[nt][r4]);
  }
}

// ===== K3: combine + Who = h @ Wout + layer-2 tables =======================
__global__ __launch_bounds__(256) void k_gemm2(const u16* __restrict__ pnum,
                                               const float* __restrict__ pden,
                                               const float* __restrict__ Wout,
                                               const float* __restrict__ aout,
                                               u16* __restrict__ whoB,
                                               float* __restrict__ r1o,
                                               u16* __restrict__ e21oh, u16* __restrict__ e202oh){
  __shared__ float Wl[8192];                  // 512 x 16
  __shared__ float hrow[16 * 516];            // combined+elu rows, padded stride
  __shared__ float sden[128];                 // den[h][n]
  int n0 = blockIdx.x * 16;
  for (int t = threadIdx.x; t < 8192; t += 256) Wl[t] = Wout[t];
  if (threadIdx.x < 128){
    int hh = threadIdx.x >> 4, nn = threadIdx.x & 15;
    float d = 0.f;
    #pragma unroll
    for (int s = 0; s < 4; ++s) d += pden[((size_t)s * 8 + hh) * 4096 + n0 + nn];
    sden[threadIdx.x] = d;
  }
  __syncthreads();
  {
    int nn = threadIdx.x >> 4;
    int fc = threadIdx.x & 15;
    int f0 = fc * 32;
    int hh = fc >> 1;
    float dinv = 1.f / sden[hh * 16 + nn];
    float v[32];
    #pragma unroll
    for (int k = 0; k < 32; ++k) v[k] = 0.f;
    #pragma unroll
    for (int s = 0; s < 4; ++s){
      const u16* p = pnum + ((size_t)s * 4096 + n0 + nn) * 512 + f0;
      #pragma unroll
      for (int q = 0; q < 4; ++q){
        uint4 raw = *(const uint4*)(p + q * 8);
        u32 rw[4] = {raw.x, raw.y, raw.z, raw.w};
        #pragma unroll
        for (int d2 = 0; d2 < 4; ++d2){
          h2 dh = u2h2(rw[d2]);
          v[q * 8 + d2 * 2]     += (float)dh.x;
          v[q * 8 + d2 * 2 + 1] += (float)dh.y;
        }
      }
    }
    #pragma unroll
    for (int k = 0; k < 32; ++k){
      float val = v[k] * dinv;
      val = val > 0.f ? val : (__expf(val) - 1.f);
      hrow[nn * 516 + f0 + k] = val;
    }
  }
  __syncthreads();
  int c  = threadIdx.x & 15;
  int rl = threadIdx.x >> 4;
  int n = n0 + rl;
  const float4* hr = (const float4*)(hrow + rl * 516);
  float acc = 0.f;
  #pragma unroll 8
  for (int f4 = 0; f4 < 128; ++f4){
    float4 hv = hr[f4];
    int f = f4 * 4;
    acc += hv.x * Wl[f * 16 + c] + hv.y * Wl[(f + 1) * 16 + c]
         + hv.z * Wl[(f + 2) * 16 + c] + hv.w * Wl[(f + 3) * 16 + c];
  }
  whoB[((size_t)(n >> 3) * 16 + c) * 8 + (n & 7)] = f2h(acc);
  float p1 = acc * aout[c], p2 = acc * aout[16 + c];
  #pragma unroll
  for (int d = 1; d < 16; d <<= 1){ p1 += __shfl_xor(p1, d, 64); p2 += __shfl_xor(p2, d, 64); }
  if (c == 0){
    r1o[n]    = __expf(-0.8f * p1);
    e21oh[n]  = f2h(__expf(p2));
    e202oh[n] = f2h(__expf(0.2f * p2));
  }
}

// ===== K4: layer-2 attention (16-way split, f16, global-direct) ============
__global__ __launch_bounds__(256) void k_att2(const u16* __restrict__ whoB,
                                              const u64* __restrict__ bits_t,
                                              const float* __restrict__ r1o,
                                              const u16* __restrict__ e21oh, const u16* __restrict__ e202oh,
                                              float* __restrict__ pnum, float* __restrict__ pden){
  __shared__ u32 smLut[4];
  int iblk  = blockIdx.x;
  int split = blockIdx.y;                     // 0..15
  int lane = threadIdx.x & 63;
  int wv   = threadIdx.x >> 6;
  int row16 = lane & 15, grp = lane >> 4;
  if (threadIdx.x < 4)
    smLut[threadIdx.x] = ((threadIdx.x & 1) ? 0xFFFFu : 0u) | ((threadIdx.x & 2) ? 0xFFFF0000u : 0u);
  __syncthreads();
  int i = iblk * 64 + wv * 16 + row16;
  u32 rb = (u32)f2h(r1o[i]); rb |= rb << 16;
  h2 rr = u2h2(rb);
  int jbeg = split * 256;
  half8 bden;
  {
    u32 z[4] = {0,0,0,0};
    if (row16 == 0){ z[0]=0x3C003C00u; z[1]=0x3C003C00u; z[2]=0x3C003C00u; z[3]=0x3C003C00u; }
    bden = pk2h8(*(uint4*)z);
  }

  f32x4 acc = {};
  f32x4 accden = {};
  #pragma unroll
  for (int c = 0; c < 4; ++c){
    int j0 = jbeg + c * 64;
    u64 mrow = bits_t[(size_t)(split * 4 + c) * 4096 + i];   // coalesced
    #pragma unroll
    for (int ks = 0; ks < 2; ++ks){
      int sb = (j0 >> 3) + ks * 4 + grp;
      half8 bf = *(const half8*)(whoB + ((size_t)sb * 16 + row16) * 8);
      uint4 e1q = *(const uint4*)(e21oh  + j0 + ks * 32 + grp * 8);
      uint4 e2q = *(const uint4*)(e202oh + j0 + ks * 32 + grp * 8);
      u32 es[4] = {e1q.x, e1q.y, e1q.z, e1q.w};
      u32 gs[4] = {e2q.x, e2q.y, e2q.z, e2q.w};
      u32 mb = ((u32)(mrow >> (ks * 32)) >> (grp * 8)) & 0xffu;
      u32 pk[4];
      #pragma unroll
      for (int t2i = 0; t2i < 4; ++t2i){
        h2 w = __builtin_elementwise_max(u2h2(es[t2i]), rr * u2h2(gs[t2i]));
        pk[t2i] = h22u(w) & smLut[(mb >> (2 * t2i)) & 3u];
      }
      half8 af = pk2h8(*(uint4*)pk);
      acc    = __builtin_amdgcn_mfma_f32_16x16x32_f16(af, bf, acc, 0, 0, 0);
      accden = __builtin_amdgcn_mfma_f32_16x16x32_f16(af, bden, accden, 0, 0, 0);
    }
  }
  #pragma unroll
  for (int r4 = 0; r4 < 4; ++r4){
    int n = iblk * 64 + wv * 16 + grp * 4 + r4;
    if (row16 == 0)
      pden[(size_t)n * 16 + split] = accden[r4];
    pnum[((size_t)n * 16 + split) * 16 + row16] = acc[r4];
  }
}

// ===== K5: combine + elu + log_softmax =====================================
__global__ __launch_bounds__(256) void k_final(const float* __restrict__ pnum,
                                               const float* __restrict__ pden,
                                               float* __restrict__ out){
  int tid = blockIdx.x * 256 + threadIdx.x;   // 65536
  int c = tid & 15;
  int n = tid >> 4;
  float num = 0.f, den = 0.f;
  #pragma unroll
  for (int s = 0; s < 16; ++s){
    num += pnum[((size_t)n * 16 + s) * 16 + c];
    den += pden[(size_t)n * 16 + s];
  }
  float v = num / den;
  v = v > 0.f ? v : (__expf(v) - 1.f);
  float m = v;
  #pragma unroll
  for (int d = 1; d < 16; d <<= 1) m = fmaxf(m, __shfl_xor(m, d, 64));
  float es = __expf(v - m), ss = es;
  #pragma unroll
  for (int d = 1; d < 16; d <<= 1) ss += __shfl_xor(ss, d, 64);
  out[(size_t)n * 16 + c] = v - m - __logf(ss);
}

// ---------------------------------------------------------------------------
extern "C" void kernel_launch(void* const* d_in, const int* in_sizes, int n_in,
                              void* d_out, int out_size, void* d_ws, size_t ws_size,
                              hipStream_t stream){
  (void)in_sizes; (void)n_in; (void)out_size; (void)ws_size;
  const float* x    = (const float*)d_in[0];
  const int*   adj  = (const int*)d_in[1];
  const float* W    = (const float*)d_in[2];
  const float* av   = (const float*)d_in[3];
  const float* Wout = (const float*)d_in[4];
  const float* aout = (const float*)d_in[5];
  float* out = (float*)d_out;
  char* ws = (char*)d_ws;

  u64*  bits_t  = (u64*)(ws + 0x0000000);        // 2 MB [64][4096]
  u16*  whB     = (u16*)(ws + 0x0200000);        // 4 MB f16 [8][j/8][o][8]
  float* r1     = (float*)(ws + 0x0600000);      // 128 KB
  u16*  e21h    = (u16*)(ws + 0x0620000);        // 64 KB f16
  u16*  e202h   = (u16*)(ws + 0x0630000);        // 64 KB f16
  u16*  pnum1   = (u16*)(ws + 0x0680000);        // 16 MB f16 [4][4096][512]
  float* pden1  = (float*)(ws + 0x1680000);      // 512 KB [4][8][4096]
  u16*  whoB    = (u16*)(ws + 0x1700000);        // 128 KB f16
  float* r1o    = (float*)(ws + 0x1720000);      // 16 KB
  u16*  e21oh   = (u16*)(ws + 0x1724000);        // 8 KB f16
  u16*  e202oh  = (u16*)(ws + 0x1726000);        // 8 KB f16
  float* pnum2  = (float*)(ws + 0x1730000);      // 4 MB [4096][16][16]
  float* pden2  = (float*)(ws + 0x1B30000);      // 256 KB
  // Wb16 aliases pnum2's region: written by k_wpack, consumed by k_gemm1,
  // then dead before k_att2 overwrites the region (stream-ordered safe).
  u16*  Wb16    = (u16*)(ws + 0x1730000);        // 512 KB f16 [8][64][64][8]

  k_wpack<<<dim3(128), dim3(256), 0, stream>>>(W, Wb16);
  k_gemm1<<<dim3(128, 8), dim3(256), 0, stream>>>(x, Wb16, av, adj, whB, bits_t, r1, e21h, e202h);
  k_att1<<<dim3(64, 8, 4), dim3(256), 0, stream>>>(whB, bits_t, r1, e21h, e202h, pnum1, pden1);
  k_gemm2<<<dim3(256), dim3(256), 0, stream>>>(pnum1, pden1, Wout, aout, whoB, r1o, e21oh, e202oh);
  k_att2<<<dim3(64, 16), dim3(256), 0, stream>>>(whoB, bits_t, r1o, e21oh, e202oh, pnum2, pden2);
  k_final<<<dim3(256), dim3(256), 0, stream>>>(pnum2, pden2, out);
}

// Round 5
// 174.373 us; speedup vs baseline: 1.1127x; 1.0207x over previous
//
#include <hip/hip_runtime.h>

// ---------------------------------------------------------------------------
// GAT (2-layer, dense mask) on gfx950 — R19.
// R18 post-mortem: int4 adj-pack = noise (178 vs 175.3). Reverted to R15 base.
// R17 isolation: att1=61us there => everything-else ~133us; after wpack(2)+
// gemm1(~40), the gemm2/att2/final tail ~90us. k_gemm2 is the structural
// worst: grid 256 = 1 block/CU (12.5% occ cap), 66KB LDS, 3 serial phases,
// 1 wave/SIMD. Floor ~5us. R19 = R15 + gemm2 redesign: 4 rows/block, grid
// 1024, LDS 8KB (Wout stays in L1 - it is exactly 32KB), 1 barrier, K-split
// dot with 2-shuffle reduce (avoids R16's 96-shuffle failure mode).
// ---------------------------------------------------------------------------

typedef _Float16 h2 __attribute__((ext_vector_type(2)));
typedef _Float16 half8 __attribute__((ext_vector_type(8)));
typedef __attribute__((ext_vector_type(4))) float f32x4;
typedef unsigned long long u64;
typedef unsigned short u16;
typedef unsigned int u32;

__device__ __forceinline__ u16 f2h(float f){
  union { _Float16 h; u16 u; } c; c.h = (_Float16)f; return c.u;
}
__device__ __forceinline__ h2 u2h2(u32 u){ union { u32 u; h2 h; } c; c.u = u; return c.h; }
__device__ __forceinline__ u32 h22u(h2 h){ union { u32 u; h2 h; } c; c.h = h; return c.u; }
__device__ __forceinline__ half8 pk2h8(uint4 v){ union { uint4 u; half8 h; } c; c.u = v; return c.h; }

__device__ __forceinline__ void async16(void* lds, const void* g){
  __builtin_amdgcn_global_load_lds((const __attribute__((address_space(1))) u32*)g,
                                   (__attribute__((address_space(3))) u32*)lds, 16, 0, 0);
}
__device__ __forceinline__ void async4(void* lds, const void* g){
  __builtin_amdgcn_global_load_lds((const __attribute__((address_space(1))) u32*)g,
                                   (__attribute__((address_space(3))) u32*)lds, 4, 0, 0);
}

// ===== K0: pack W f32 -> f16 B-layout [h][fgb(64)][o(64)][q(8)] ============
__global__ __launch_bounds__(256) void k_wpack(const float* __restrict__ W,
                                               u16* __restrict__ Wb16){
  int t = blockIdx.x * 256 + threadIdx.x;   // 0..32767 = 8 h x 64 fgb x 64 o
  int o   = t & 63;
  int fgb = (t >> 6) & 63;
  int h   = t >> 12;
  const float* src = W + ((size_t)h * 512 + fgb * 8) * 64 + o;
  u32 pk[4];
  #pragma unroll
  for (int p = 0; p < 4; ++p)
    pk[p] = (u32)f2h(src[(2 * p) * 64]) | ((u32)f2h(src[(2 * p + 1) * 64]) << 16);
  *(uint4*)(Wb16 + ((size_t)h * 4096 + fgb * 64 + o) * 8) = *(uint4*)pk;
}

// ===== K1: Wh = x @ W[h] (B-frags from global Wb16) + tables + whB,        =
// =====     plus block-specialized adj bitmask pack (bx >= 64)              =
__global__ __launch_bounds__(256) void k_gemm1(const float* __restrict__ x,
                                               const u16* __restrict__ Wb16,
                                               const float* __restrict__ av,
                                               const int* __restrict__ adj,
                                               u16* __restrict__ whB,
                                               u64* __restrict__ bits_t,
                                               float* __restrict__ r1,
                                               u16* __restrict__ e21h, u16* __restrict__ e202h){
  __shared__ u16 tr[4096];                 // 8 KB transpose buffer (only LDS)
  int h    = blockIdx.y;
  int bx   = blockIdx.x;
  int tid  = threadIdx.x;
  int lane = tid & 63;
  int wv   = tid >> 6;

  if (bx >= 64){
    // ---- adj-pack slice (transposed bitmask; independent of gemm) ----
    int B = h * 64 + (bx - 64);            // 0..511
    int uid0 = B * 512 + wv * 128;
    for (int k = 0; k < 128; k += 8){
      int v[8];
      #pragma unroll
      for (int q = 0; q < 8; ++q){
        int uid = uid0 + k + q;
        v[q] = adj[(size_t)(uid >> 6) * 4096 + ((uid & 63) << 6) + lane];
      }
      u64 m[8];
      #pragma unroll
      for (int q = 0; q < 8; ++q) m[q] = __ballot(v[q] != 0);
      if (lane == 0){
        #pragma unroll
        for (int q = 0; q < 8; ++q){
          int uid = uid0 + k + q;
          bits_t[(size_t)(uid & 63) * 4096 + (uid >> 6)] = m[q];
        }
      }
    }
    return;
  }

  // ---- gemm path ----
  int row16 = lane & 15, grp = lane >> 4;
  int n0 = bx * 64;
  int n0w = n0 + wv * 16;
  const u16* wb = Wb16 + (size_t)h * 32768;

  f32x4 acc[4] = {};
  #pragma unroll 4
  for (int ks = 0; ks < 16; ++ks){
    int fgb = ks * 4 + grp;
    const float* xs = x + (size_t)(n0w + row16) * 512 + fgb * 8;
    float4 xv0 = ((const float4*)xs)[0];
    float4 xv1 = ((const float4*)xs)[1];
    u32 ax[4];
    ax[0] = (u32)f2h(xv0.x) | ((u32)f2h(xv0.y) << 16);
    ax[1] = (u32)f2h(xv0.z) | ((u32)f2h(xv0.w) << 16);
    ax[2] = (u32)f2h(xv1.x) | ((u32)f2h(xv1.y) << 16);
    ax[3] = (u32)f2h(xv1.z) | ((u32)f2h(xv1.w) << 16);
    half8 af = pk2h8(*(uint4*)ax);
    #pragma unroll
    for (int nt = 0; nt < 4; ++nt){
      half8 bf = *(const half8*)(wb + ((size_t)fgb * 64 + nt * 16 + row16) * 8);
      acc[nt] = __builtin_amdgcn_mfma_f32_16x16x32_f16(af, bf, acc[nt], 0, 0, 0);
    }
  }
  // ---- scale-free score tables ----
  float a1v[4], a2v[4];
  #pragma unroll
  for (int nt = 0; nt < 4; ++nt){
    a1v[nt] = av[h * 128 + nt * 16 + row16];
    a2v[nt] = av[h * 128 + 64 + nt * 16 + row16];
  }
  #pragma unroll
  for (int r = 0; r < 4; ++r){
    float p1 = acc[0][r]*a1v[0] + acc[1][r]*a1v[1] + acc[2][r]*a1v[2] + acc[3][r]*a1v[3];
    float p2 = acc[0][r]*a2v[0] + acc[1][r]*a2v[1] + acc[2][r]*a2v[2] + acc[3][r]*a2v[3];
    #pragma unroll
    for (int d = 1; d < 16; d <<= 1){ p1 += __shfl_xor(p1, d, 64); p2 += __shfl_xor(p2, d, 64); }
    if (row16 == 0){
      int idx = h * 4096 + n0w + grp * 4 + r;
      r1[idx]    = __expf(-0.8f * p1);     // row scale e^{-0.8 s1}
      e21h[idx]  = f2h(__expf(p2));
      e202h[idx] = f2h(__expf(0.2f * p2));
    }
  }
  // ---- whB f16 pack via LDS transpose ----
  #pragma unroll
  for (int nt = 0; nt < 4; ++nt)
    #pragma unroll
    for (int r = 0; r < 4; ++r){
      int jl = wv * 16 + grp * 4 + r;
      int o  = nt * 16 + row16;
      tr[((jl >> 3) * 64 + o) * 8 + (jl & 7)] = f2h(acc[nt][r]);
    }
  __syncthreads();
  u16* dst = whB + (size_t)h * 262144 + (size_t)n0 * 64;
  #pragma unroll
  for (int q = 0; q < 2; ++q)
    *(uint4*)(dst + (tid * 2 + q) * 8) = *(const uint4*)(tr + (tid * 2 + q) * 8);
}

// ===== K2: layer-1 attention (LDS dbuf, f16 + packed w-gen) ================
__global__ __launch_bounds__(256) void k_att1(const u16* __restrict__ whB,
                                              const u64* __restrict__ bits_t,
                                              const float* __restrict__ r1,
                                              const u16* __restrict__ e21h, const u16* __restrict__ e202h,
                                              u16* __restrict__ pnum, float* __restrict__ pden){
  __shared__ u16  smB[2][4096];            // 64 j x 64 o f16, [j/8][o][j&7]
  __shared__ u32  smT[2][2][64];           // staged f16 tables
  __shared__ u32  smLut[4];
  int h     = blockIdx.y;
  int iblk  = blockIdx.x;
  int split = blockIdx.z;
  int lane = threadIdx.x & 63;
  int wv   = threadIdx.x >> 6;
  int row16 = lane & 15, grp = lane >> 4;
  if (threadIdx.x < 4)
    smLut[threadIdx.x] = ((threadIdx.x & 1) ? 0xFFFFu : 0u) | ((threadIdx.x & 2) ? 0xFFFF0000u : 0u);
  int i = iblk * 64 + wv * 16 + row16;
  int hoff = h * 4096;
  u32 rb = (u32)f2h(r1[hoff + i]); rb |= rb << 16;
  h2 rr = u2h2(rb);
  const u16* whBh = whB + (size_t)h * 262144;
  int jbeg = split * 1024;

  half8 bden;                              // ones-column B frag for den
  {
    u32 z[4] = {0,0,0,0};
    if (row16 == 0){ z[0]=0x3C003C00u; z[1]=0x3C003C00u; z[2]=0x3C003C00u; z[3]=0x3C003C00u; }
    bden = pk2h8(*(uint4*)z);
  }

  auto stage = [&](int bb, int j0){
    const char* g = (const char*)whBh + (size_t)j0 * 128 + wv * 2048 + lane * 16;
    char* l = (char*)(&smB[bb][0]) + wv * 2048;
    async16(l, g);
    async16(l + 1024, g + 1024);
    if (wv == 0)      async4(&smT[bb][0][0], (const char*)(e21h  + hoff + j0) + lane * 4);
    else if (wv == 1) async4(&smT[bb][1][0], (const char*)(e202h + hoff + j0) + lane * 4);
  };

  f32x4 acc[4] = {};
  f32x4 accden = {};
  stage(0, jbeg);
  for (int c = 0; c < 16; ++c){
    int bb = c & 1;
    u64 mrow = bits_t[(size_t)(split * 16 + c) * 4096 + i];   // coalesced
    __syncthreads();                       // buf bb staged; buf bb^1 free
    if (c < 15) stage(bb ^ 1, jbeg + (c + 1) * 64);
    #pragma unroll
    for (int ks = 0; ks < 2; ++ks){
      uint4 e1q = *(const uint4*)((const char*)&smT[bb][0][0] + ks * 64 + grp * 16);
      uint4 e2q = *(const uint4*)((const char*)&smT[bb][1][0] + ks * 64 + grp * 16);
      u32 es[4] = {e1q.x, e1q.y, e1q.z, e1q.w};
      u32 gs[4] = {e2q.x, e2q.y, e2q.z, e2q.w};
      const u16* bbase = &smB[bb][(ks * 4 + grp) * 512];
      half8 bf0 = *(const half8*)(bbase + (0 * 16 + row16) * 8);
      half8 bf1 = *(const half8*)(bbase + (1 * 16 + row16) * 8);
      half8 bf2 = *(const half8*)(bbase + (2 * 16 + row16) * 8);
      half8 bf3 = *(const half8*)(bbase + (3 * 16 + row16) * 8);
      u32 mb = ((u32)(mrow >> (ks * 32)) >> (grp * 8)) & 0xffu;
      u32 pk[4];
      #pragma unroll
      for (int t2i = 0; t2i < 4; ++t2i){
        h2 w = __builtin_elementwise_max(u2h2(es[t2i]), rr * u2h2(gs[t2i]));
        pk[t2i] = h22u(w) & smLut[(mb >> (2 * t2i)) & 3u];
      }
      half8 af = pk2h8(*(uint4*)pk);
      acc[0] = __builtin_amdgcn_mfma_f32_16x16x32_f16(af, bf0, acc[0], 0, 0, 0);
      acc[1] = __builtin_amdgcn_mfma_f32_16x16x32_f16(af, bf1, acc[1], 0, 0, 0);
      acc[2] = __builtin_amdgcn_mfma_f32_16x16x32_f16(af, bf2, acc[2], 0, 0, 0);
      acc[3] = __builtin_amdgcn_mfma_f32_16x16x32_f16(af, bf3, acc[3], 0, 0, 0);
      accden = __builtin_amdgcn_mfma_f32_16x16x32_f16(af, bden, accden, 0, 0, 0);
    }
  }

  #pragma unroll
  for (int r4 = 0; r4 < 4; ++r4){
    int n = iblk * 64 + wv * 16 + grp * 4 + r4;
    if (row16 == 0)
      pden[((size_t)split * 8 + h) * 4096 + n] = accden[r4];
    u16* dst = pnum + ((size_t)split * 4096 + n) * 512 + h * 64 + row16;
    #pragma unroll
    for (int nt = 0; nt < 4; ++nt)
      dst[nt * 16] = f2h(acc[nt][r4]);
  }
}

// ===== K3: combine + Who = h @ Wout + layer-2 tables (4 rows/block) ========
__global__ __launch_bounds__(256) void k_gemm2(const u16* __restrict__ pnum,
                                               const float* __restrict__ pden,
                                               const float* __restrict__ Wout,
                                               const float* __restrict__ aout,
                                               u16* __restrict__ whoB,
                                               float* __restrict__ r1o,
                                               u16* __restrict__ e21oh, u16* __restrict__ e202oh){
  __shared__ float hrowf[4][512];             // 8 KB combined+elu rows (f32)
  int n0  = blockIdx.x * 4;
  int tid = threadIdx.x;
  // ---- phase A: combine 4 splits + ELU, 64 threads per row ----
  {
    int nn = tid >> 6;                        // row 0..3
    int fc = tid & 63;                        // f-chunk 0..63
    int f0 = fc * 8;
    int hh = fc >> 3;                         // head = f0/64
    int n  = n0 + nn;
    float v[8] = {0.f,0.f,0.f,0.f,0.f,0.f,0.f,0.f};
    float d = 0.f;
    #pragma unroll
    for (int s = 0; s < 4; ++s){
      uint4 raw = *(const uint4*)(pnum + ((size_t)s * 4096 + n) * 512 + f0);
      u32 rw[4] = {raw.x, raw.y, raw.z, raw.w};
      #pragma unroll
      for (int q = 0; q < 4; ++q){
        h2 dh = u2h2(rw[q]);
        v[q * 2]     += (float)dh.x;
        v[q * 2 + 1] += (float)dh.y;
      }
      d += pden[((size_t)s * 8 + hh) * 4096 + n];
    }
    float dinv = 1.f / d;
    #pragma unroll
    for (int k = 0; k < 8; ++k){
      float val = v[k] * dinv;
      hrowf[nn][f0 + k] = val > 0.f ? val : (__expf(val) - 1.f);
    }
  }
  __syncthreads();
  // ---- phase B: who[n][c] via K-split dot (Wout stays in L1: 32 KB) ----
  int rl = tid >> 6;                          // row 0..3
  int kq = (tid >> 4) & 3;                    // K-quarter 0..3
  int c  = tid & 15;                          // out col 0..15
  int n  = n0 + rl;
  const float* hr = &hrowf[rl][kq * 128];
  const float* wp = Wout + (size_t)(kq * 128) * 16 + c;
  float a0 = 0.f, a1 = 0.f;
  #pragma unroll 16
  for (int f = 0; f < 128; f += 2){
    a0 += hr[f]     * wp[f * 16];
    a1 += hr[f + 1] * wp[f * 16 + 16];
  }
  float acc = a0 + a1;
  acc += __shfl_xor(acc, 16, 64);             // reduce over kq
  acc += __shfl_xor(acc, 32, 64);
  int lane = tid & 63;
  if ((lane >> 4) == 0)
    whoB[((size_t)(n >> 3) * 16 + c) * 8 + (n & 7)] = f2h(acc);
  float p1 = acc * aout[c], p2 = acc * aout[16 + c];
  #pragma unroll
  for (int d = 1; d < 16; d <<= 1){ p1 += __shfl_xor(p1, d, 64); p2 += __shfl_xor(p2, d, 64); }
  if (lane == 0){
    r1o[n]    = __expf(-0.8f * p1);
    e21oh[n]  = f2h(__expf(p2));
    e202oh[n] = f2h(__expf(0.2f * p2));
  }
}

// ===== K4: layer-2 attention (16-way split, f16, global-direct) ============
__global__ __launch_bounds__(256) void k_att2(const u16* __restrict__ whoB,
                                              const u64* __restrict__ bits_t,
                                              const float* __restrict__ r1o,
                                              const u16* __restrict__ e21oh, const u16* __restrict__ e202oh,
                                              float* __restrict__ pnum, float* __restrict__ pden){
  __shared__ u32 smLut[4];
  int iblk  = blockIdx.x;
  int split = blockIdx.y;                     // 0..15
  int lane = threadIdx.x & 63;
  int wv   = threadIdx.x >> 6;
  int row16 = lane & 15, grp = lane >> 4;
  if (threadIdx.x < 4)
    smLut[threadIdx.x] = ((threadIdx.x & 1) ? 0xFFFFu : 0u) | ((threadIdx.x & 2) ? 0xFFFF0000u : 0u);
  __syncthreads();
  int i = iblk * 64 + wv * 16 + row16;
  u32 rb = (u32)f2h(r1o[i]); rb |= rb << 16;
  h2 rr = u2h2(rb);
  int jbeg = split * 256;
  half8 bden;
  {
    u32 z[4] = {0,0,0,0};
    if (row16 == 0){ z[0]=0x3C003C00u; z[1]=0x3C003C00u; z[2]=0x3C003C00u; z[3]=0x3C003C00u; }
    bden = pk2h8(*(uint4*)z);
  }

  f32x4 acc = {};
  f32x4 accden = {};
  #pragma unroll
  for (int c = 0; c < 4; ++c){
    int j0 = jbeg + c * 64;
    u64 mrow = bits_t[(size_t)(split * 4 + c) * 4096 + i];   // coalesced
    #pragma unroll
    for (int ks = 0; ks < 2; ++ks){
      int sb = (j0 >> 3) + ks * 4 + grp;
      half8 bf = *(const half8*)(whoB + ((size_t)sb * 16 + row16) * 8);
      uint4 e1q = *(const uint4*)(e21oh  + j0 + ks * 32 + grp * 8);
      uint4 e2q = *(const uint4*)(e202oh + j0 + ks * 32 + grp * 8);
      u32 es[4] = {e1q.x, e1q.y, e1q.z, e1q.w};
      u32 gs[4] = {e2q.x, e2q.y, e2q.z, e2q.w};
      u32 mb = ((u32)(mrow >> (ks * 32)) >> (grp * 8)) & 0xffu;
      u32 pk[4];
      #pragma unroll
      for (int t2i = 0; t2i < 4; ++t2i){
        h2 w = __builtin_elementwise_max(u2h2(es[t2i]), rr * u2h2(gs[t2i]));
        pk[t2i] = h22u(w) & smLut[(mb >> (2 * t2i)) & 3u];
      }
      half8 af = pk2h8(*(uint4*)pk);
      acc    = __builtin_amdgcn_mfma_f32_16x16x32_f16(af, bf, acc, 0, 0, 0);
      accden = __builtin_amdgcn_mfma_f32_16x16x32_f16(af, bden, accden, 0, 0, 0);
    }
  }
  #pragma unroll
  for (int r4 = 0; r4 < 4; ++r4){
    int n = iblk * 64 + wv * 16 + grp * 4 + r4;
    if (row16 == 0)
      pden[(size_t)n * 16 + split] = accden[r4];
    pnum[((size_t)n * 16 + split) * 16 + row16] = acc[r4];
  }
}

// ===== K5: combine + elu + log_softmax =====================================
__global__ __launch_bounds__(256) void k_final(const float* __restrict__ pnum,
                                               const float* __restrict__ pden,
                                               float* __restrict__ out){
  int tid = blockIdx.x * 256 + threadIdx.x;   // 65536
  int c = tid & 15;
  int n = tid >> 4;
  float num = 0.f, den = 0.f;
  #pragma unroll
  for (int s = 0; s < 16; ++s){
    num += pnum[((size_t)n * 16 + s) * 16 + c];
    den += pden[(size_t)n * 16 + s];
  }
  float v = num / den;
  v = v > 0.f ? v : (__expf(v) - 1.f);
  float m = v;
  #pragma unroll
  for (int d = 1; d < 16; d <<= 1) m = fmaxf(m, __shfl_xor(m, d, 64));
  float es = __expf(v - m), ss = es;
  #pragma unroll
  for (int d = 1; d < 16; d <<= 1) ss += __shfl_xor(ss, d, 64);
  out[(size_t)n * 16 + c] = v - m - __logf(ss);
}

// ---------------------------------------------------------------------------
extern "C" void kernel_launch(void* const* d_in, const int* in_sizes, int n_in,
                              void* d_out, int out_size, void* d_ws, size_t ws_size,
                              hipStream_t stream){
  (void)in_sizes; (void)n_in; (void)out_size; (void)ws_size;
  const float* x    = (const float*)d_in[0];
  const int*   adj  = (const int*)d_in[1];
  const float* W    = (const float*)d_in[2];
  const float* av   = (const float*)d_in[3];
  const float* Wout = (const float*)d_in[4];
  const float* aout = (const float*)d_in[5];
  float* out = (float*)d_out;
  char* ws = (char*)d_ws;

  u64*  bits_t  = (u64*)(ws + 0x0000000);        // 2 MB [64][4096]
  u16*  whB     = (u16*)(ws + 0x0200000);        // 4 MB f16 [8][j/8][o][8]
  float* r1     = (float*)(ws + 0x0600000);      // 128 KB
  u16*  e21h    = (u16*)(ws + 0x0620000);        // 64 KB f16
  u16*  e202h   = (u16*)(ws + 0x0630000);        // 64 KB f16
  u16*  pnum1   = (u16*)(ws + 0x0680000);        // 16 MB f16 [4][4096][512]
  float* pden1  = (float*)(ws + 0x1680000);      // 512 KB [4][8][4096]
  u16*  whoB    = (u16*)(ws + 0x1700000);        // 128 KB f16
  float* r1o    = (float*)(ws + 0x1720000);      // 16 KB
  u16*  e21oh   = (u16*)(ws + 0x1724000);        // 8 KB f16
  u16*  e202oh  = (u16*)(ws + 0x1726000);        // 8 KB f16
  float* pnum2  = (float*)(ws + 0x1730000);      // 4 MB [4096][16][16]
  float* pden2  = (float*)(ws + 0x1B30000);      // 256 KB
  // Wb16 aliases pnum2's region: written by k_wpack, consumed by k_gemm1,
  // then dead before k_att2 overwrites the region (stream-ordered safe).
  u16*  Wb16    = (u16*)(ws + 0x1730000);        // 512 KB f16 [8][64][64][8]

  k_wpack<<<dim3(128), dim3(256), 0, stream>>>(W, Wb16);
  k_gemm1<<<dim3(128, 8), dim3(256), 0, stream>>>(x, Wb16, av, adj, whB, bits_t, r1, e21h, e202h);
  k_att1<<<dim3(64, 8, 4), dim3(256), 0, stream>>>(whB, bits_t, r1, e21h, e202h, pnum1, pden1);
  k_gemm2<<<dim3(1024), dim3(256), 0, stream>>>(pnum1, pden1, Wout, aout, whoB, r1o, e21oh, e202oh);
  k_att2<<<dim3(64, 16), dim3(256), 0, stream>>>(whoB, bits_t, r1o, e21oh, e202oh, pnum2, pden2);
  k_final<<<dim3(256), dim3(256), 0, stream>>>(pnum2, pden2, out);
}

// Round 6
// 170.362 us; speedup vs baseline: 1.1389x; 1.0235x over previous
//
#include <hip/hip_runtime.h>

// ---------------------------------------------------------------------------
// GAT (2-layer, dense mask) on gfx950 — R20.
// Budget (verified): att1 ~41us (R17 isolation), gemm1 ~40-43 (R14 measured),
// tail kernels small, ~50us fixed overhead. R19's gemm2 redesign = no change
// (kept: simpler, equal). R20 = R19 + ONE change: att1 KVBLK 64->128.
// Mechanism: 16 -> 8 c-iterations => half the {stage -> vmcnt(0) drain ->
// s_barrier} events (the m97 barrier-stall mechanism), 2x MFMA per barrier
// (10->20/wave). LDS 16.5->33 KB => 4 blocks/CU (16 waves, 4/SIMD) - enough
// TLP for L2-hot stages; barrier drain is a block-global stall so halving it
// wins over the lost occupancy.
// ---------------------------------------------------------------------------

typedef _Float16 h2 __attribute__((ext_vector_type(2)));
typedef _Float16 half8 __attribute__((ext_vector_type(8)));
typedef __attribute__((ext_vector_type(4))) float f32x4;
typedef unsigned long long u64;
typedef unsigned short u16;
typedef unsigned int u32;

__device__ __forceinline__ u16 f2h(float f){
  union { _Float16 h; u16 u; } c; c.h = (_Float16)f; return c.u;
}
__device__ __forceinline__ h2 u2h2(u32 u){ union { u32 u; h2 h; } c; c.u = u; return c.h; }
__device__ __forceinline__ u32 h22u(h2 h){ union { u32 u; h2 h; } c; c.h = h; return c.u; }
__device__ __forceinline__ half8 pk2h8(uint4 v){ union { uint4 u; half8 h; } c; c.u = v; return c.h; }

__device__ __forceinline__ void async16(void* lds, const void* g){
  __builtin_amdgcn_global_load_lds((const __attribute__((address_space(1))) u32*)g,
                                   (__attribute__((address_space(3))) u32*)lds, 16, 0, 0);
}
__device__ __forceinline__ void async4(void* lds, const void* g){
  __builtin_amdgcn_global_load_lds((const __attribute__((address_space(1))) u32*)g,
                                   (__attribute__((address_space(3))) u32*)lds, 4, 0, 0);
}

// ===== K0: pack W f32 -> f16 B-layout [h][fgb(64)][o(64)][q(8)] ============
__global__ __launch_bounds__(256) void k_wpack(const float* __restrict__ W,
                                               u16* __restrict__ Wb16){
  int t = blockIdx.x * 256 + threadIdx.x;   // 0..32767 = 8 h x 64 fgb x 64 o
  int o   = t & 63;
  int fgb = (t >> 6) & 63;
  int h   = t >> 12;
  const float* src = W + ((size_t)h * 512 + fgb * 8) * 64 + o;
  u32 pk[4];
  #pragma unroll
  for (int p = 0; p < 4; ++p)
    pk[p] = (u32)f2h(src[(2 * p) * 64]) | ((u32)f2h(src[(2 * p + 1) * 64]) << 16);
  *(uint4*)(Wb16 + ((size_t)h * 4096 + fgb * 64 + o) * 8) = *(uint4*)pk;
}

// ===== K1: Wh = x @ W[h] (B-frags from global Wb16) + tables + whB,        =
// =====     plus block-specialized adj bitmask pack (bx >= 64)              =
__global__ __launch_bounds__(256) void k_gemm1(const float* __restrict__ x,
                                               const u16* __restrict__ Wb16,
                                               const float* __restrict__ av,
                                               const int* __restrict__ adj,
                                               u16* __restrict__ whB,
                                               u64* __restrict__ bits_t,
                                               float* __restrict__ r1,
                                               u16* __restrict__ e21h, u16* __restrict__ e202h){
  __shared__ u16 tr[4096];                 // 8 KB transpose buffer (only LDS)
  int h    = blockIdx.y;
  int bx   = blockIdx.x;
  int tid  = threadIdx.x;
  int lane = tid & 63;
  int wv   = tid >> 6;

  if (bx >= 64){
    // ---- adj-pack slice (transposed bitmask; independent of gemm) ----
    int B = h * 64 + (bx - 64);            // 0..511
    int uid0 = B * 512 + wv * 128;
    for (int k = 0; k < 128; k += 8){
      int v[8];
      #pragma unroll
      for (int q = 0; q < 8; ++q){
        int uid = uid0 + k + q;
        v[q] = adj[(size_t)(uid >> 6) * 4096 + ((uid & 63) << 6) + lane];
      }
      u64 m[8];
      #pragma unroll
      for (int q = 0; q < 8; ++q) m[q] = __ballot(v[q] != 0);
      if (lane == 0){
        #pragma unroll
        for (int q = 0; q < 8; ++q){
          int uid = uid0 + k + q;
          bits_t[(size_t)(uid & 63) * 4096 + (uid >> 6)] = m[q];
        }
      }
    }
    return;
  }

  // ---- gemm path ----
  int row16 = lane & 15, grp = lane >> 4;
  int n0 = bx * 64;
  int n0w = n0 + wv * 16;
  const u16* wb = Wb16 + (size_t)h * 32768;

  f32x4 acc[4] = {};
  #pragma unroll 4
  for (int ks = 0; ks < 16; ++ks){
    int fgb = ks * 4 + grp;
    const float* xs = x + (size_t)(n0w + row16) * 512 + fgb * 8;
    float4 xv0 = ((const float4*)xs)[0];
    float4 xv1 = ((const float4*)xs)[1];
    u32 ax[4];
    ax[0] = (u32)f2h(xv0.x) | ((u32)f2h(xv0.y) << 16);
    ax[1] = (u32)f2h(xv0.z) | ((u32)f2h(xv0.w) << 16);
    ax[2] = (u32)f2h(xv1.x) | ((u32)f2h(xv1.y) << 16);
    ax[3] = (u32)f2h(xv1.z) | ((u32)f2h(xv1.w) << 16);
    half8 af = pk2h8(*(uint4*)ax);
    #pragma unroll
    for (int nt = 0; nt < 4; ++nt){
      half8 bf = *(const half8*)(wb + ((size_t)fgb * 64 + nt * 16 + row16) * 8);
      acc[nt] = __builtin_amdgcn_mfma_f32_16x16x32_f16(af, bf, acc[nt], 0, 0, 0);
    }
  }
  // ---- scale-free score tables ----
  float a1v[4], a2v[4];
  #pragma unroll
  for (int nt = 0; nt < 4; ++nt){
    a1v[nt] = av[h * 128 + nt * 16 + row16];
    a2v[nt] = av[h * 128 + 64 + nt * 16 + row16];
  }
  #pragma unroll
  for (int r = 0; r < 4; ++r){
    float p1 = acc[0][r]*a1v[0] + acc[1][r]*a1v[1] + acc[2][r]*a1v[2] + acc[3][r]*a1v[3];
    float p2 = acc[0][r]*a2v[0] + acc[1][r]*a2v[1] + acc[2][r]*a2v[2] + acc[3][r]*a2v[3];
    #pragma unroll
    for (int d = 1; d < 16; d <<= 1){ p1 += __shfl_xor(p1, d, 64); p2 += __shfl_xor(p2, d, 64); }
    if (row16 == 0){
      int idx = h * 4096 + n0w + grp * 4 + r;
      r1[idx]    = __expf(-0.8f * p1);     // row scale e^{-0.8 s1}
      e21h[idx]  = f2h(__expf(p2));
      e202h[idx] = f2h(__expf(0.2f * p2));
    }
  }
  // ---- whB f16 pack via LDS transpose ----
  #pragma unroll
  for (int nt = 0; nt < 4; ++nt)
    #pragma unroll
    for (int r = 0; r < 4; ++r){
      int jl = wv * 16 + grp * 4 + r;
      int o  = nt * 16 + row16;
      tr[((jl >> 3) * 64 + o) * 8 + (jl & 7)] = f2h(acc[nt][r]);
    }
  __syncthreads();
  u16* dst = whB + (size_t)h * 262144 + (size_t)n0 * 64;
  #pragma unroll
  for (int q = 0; q < 2; ++q)
    *(uint4*)(dst + (tid * 2 + q) * 8) = *(const uint4*)(tr + (tid * 2 + q) * 8);
}

// ===== K2: layer-1 attention (LDS dbuf, KVBLK=128, f16 packed w-gen) =======
__global__ __launch_bounds__(256) void k_att1(const u16* __restrict__ whB,
                                              const u64* __restrict__ bits_t,
                                              const float* __restrict__ r1,
                                              const u16* __restrict__ e21h, const u16* __restrict__ e202h,
                                              u16* __restrict__ pnum, float* __restrict__ pden){
  __shared__ u16  smB[2][8192];            // 128 j x 64 o f16, [j/8][o][j&7]
  __shared__ u32  smT[2][2][64];           // staged f16 tables (256 B each)
  __shared__ u32  smLut[4];
  int h     = blockIdx.y;
  int iblk  = blockIdx.x;
  int split = blockIdx.z;
  int lane = threadIdx.x & 63;
  int wv   = threadIdx.x >> 6;
  int tid  = threadIdx.x;
  int row16 = lane & 15, grp = lane >> 4;
  if (threadIdx.x < 4)
    smLut[threadIdx.x] = ((threadIdx.x & 1) ? 0xFFFFu : 0u) | ((threadIdx.x & 2) ? 0xFFFF0000u : 0u);
  int i = iblk * 64 + wv * 16 + row16;
  int hoff = h * 4096;
  u32 rb = (u32)f2h(r1[hoff + i]); rb |= rb << 16;
  h2 rr = u2h2(rb);
  const u16* whBh = whB + (size_t)h * 262144;
  int jbeg = split * 1024;

  half8 bden;                              // ones-column B frag for den
  {
    u32 z[4] = {0,0,0,0};
    if (row16 == 0){ z[0]=0x3C003C00u; z[1]=0x3C003C00u; z[2]=0x3C003C00u; z[3]=0x3C003C00u; }
    bden = pk2h8(*(uint4*)z);
  }

  auto stage = [&](int bb, int j0){
    // 16 KB B-tile: 4 x async16 per thread, fully contiguous
    const char* g = (const char*)whBh + (size_t)j0 * 128 + tid * 16;
    char* l = (char*)(&smB[bb][0]) + tid * 16;
    #pragma unroll
    for (int k = 0; k < 4; ++k)
      async16(l + k * 4096, g + k * 4096);
    // 256 B per table = 128 f16 (exactly one KVBLK)
    if (wv == 0)      async4(&smT[bb][0][0], (const char*)(e21h  + hoff + j0) + lane * 4);
    else if (wv == 1) async4(&smT[bb][1][0], (const char*)(e202h + hoff + j0) + lane * 4);
  };

  f32x4 acc[4] = {};
  f32x4 accden = {};
  stage(0, jbeg);
  for (int c = 0; c < 8; ++c){
    int bb = c & 1;
    u64 mrow0 = bits_t[(size_t)(split * 16 + c * 2)     * 4096 + i];   // coalesced
    u64 mrow1 = bits_t[(size_t)(split * 16 + c * 2 + 1) * 4096 + i];
    __syncthreads();                       // buf bb staged; buf bb^1 free
    if (c < 7) stage(bb ^ 1, jbeg + (c + 1) * 128);
    #pragma unroll
    for (int ks = 0; ks < 4; ++ks){
      uint4 e1q = *(const uint4*)((const char*)&smT[bb][0][0] + ks * 64 + grp * 16);
      uint4 e2q = *(const uint4*)((const char*)&smT[bb][1][0] + ks * 64 + grp * 16);
      u32 es[4] = {e1q.x, e1q.y, e1q.z, e1q.w};
      u32 gs[4] = {e2q.x, e2q.y, e2q.z, e2q.w};
      const u16* bbase = &smB[bb][(ks * 4 + grp) * 512];
      half8 bf0 = *(const half8*)(bbase + (0 * 16 + row16) * 8);
      half8 bf1 = *(const half8*)(bbase + (1 * 16 + row16) * 8);
      half8 bf2 = *(const half8*)(bbase + (2 * 16 + row16) * 8);
      half8 bf3 = *(const half8*)(bbase + (3 * 16 + row16) * 8);
      u64 mrow = (ks < 2) ? mrow0 : mrow1;
      u32 mb = ((u32)(mrow >> ((ks & 1) * 32)) >> (grp * 8)) & 0xffu;
      u32 pk[4];
      #pragma unroll
      for (int t2i = 0; t2i < 4; ++t2i){
        h2 w = __builtin_elementwise_max(u2h2(es[t2i]), rr * u2h2(gs[t2i]));
        pk[t2i] = h22u(w) & smLut[(mb >> (2 * t2i)) & 3u];
      }
      half8 af = pk2h8(*(uint4*)pk);
      acc[0] = __builtin_amdgcn_mfma_f32_16x16x32_f16(af, bf0, acc[0], 0, 0, 0);
      acc[1] = __builtin_amdgcn_mfma_f32_16x16x32_f16(af, bf1, acc[1], 0, 0, 0);
      acc[2] = __builtin_amdgcn_mfma_f32_16x16x32_f16(af, bf2, acc[2], 0, 0, 0);
      acc[3] = __builtin_amdgcn_mfma_f32_16x16x32_f16(af, bf3, acc[3], 0, 0, 0);
      accden = __builtin_amdgcn_mfma_f32_16x16x32_f16(af, bden, accden, 0, 0, 0);
    }
  }

  #pragma unroll
  for (int r4 = 0; r4 < 4; ++r4){
    int n = iblk * 64 + wv * 16 + grp * 4 + r4;
    if (row16 == 0)
      pden[((size_t)split * 8 + h) * 4096 + n] = accden[r4];
    u16* dst = pnum + ((size_t)split * 4096 + n) * 512 + h * 64 + row16;
    #pragma unroll
    for (int nt = 0; nt < 4; ++nt)
      dst[nt * 16] = f2h(acc[nt][r4]);
  }
}

// ===== K3: combine + Who = h @ Wout + layer-2 tables (4 rows/block) ========
__global__ __launch_bounds__(256) void k_gemm2(const u16* __restrict__ pnum,
                                               const float* __restrict__ pden,
                                               const float* __restrict__ Wout,
                                               const float* __restrict__ aout,
                                               u16* __restrict__ whoB,
                                               float* __restrict__ r1o,
                                               u16* __restrict__ e21oh, u16* __restrict__ e202oh){
  __shared__ float hrowf[4][512];             // 8 KB combined+elu rows (f32)
  int n0  = blockIdx.x * 4;
  int tid = threadIdx.x;
  // ---- phase A: combine 4 splits + ELU, 64 threads per row ----
  {
    int nn = tid >> 6;                        // row 0..3
    int fc = tid & 63;                        // f-chunk 0..63
    int f0 = fc * 8;
    int hh = fc >> 3;                         // head = f0/64
    int n  = n0 + nn;
    float v[8] = {0.f,0.f,0.f,0.f,0.f,0.f,0.f,0.f};
    float d = 0.f;
    #pragma unroll
    for (int s = 0; s < 4; ++s){
      uint4 raw = *(const uint4*)(pnum + ((size_t)s * 4096 + n) * 512 + f0);
      u32 rw[4] = {raw.x, raw.y, raw.z, raw.w};
      #pragma unroll
      for (int q = 0; q < 4; ++q){
        h2 dh = u2h2(rw[q]);
        v[q * 2]     += (float)dh.x;
        v[q * 2 + 1] += (float)dh.y;
      }
      d += pden[((size_t)s * 8 + hh) * 4096 + n];
    }
    float dinv = 1.f / d;
    #pragma unroll
    for (int k = 0; k < 8; ++k){
      float val = v[k] * dinv;
      hrowf[nn][f0 + k] = val > 0.f ? val : (__expf(val) - 1.f);
    }
  }
  __syncthreads();
  // ---- phase B: who[n][c] via K-split dot (Wout stays in L1: 32 KB) ----
  int rl = tid >> 6;                          // row 0..3
  int kq = (tid >> 4) & 3;                    // K-quarter 0..3
  int c  = tid & 15;                          // out col 0..15
  int n  = n0 + rl;
  const float* hr = &hrowf[rl][kq * 128];
  const float* wp = Wout + (size_t)(kq * 128) * 16 + c;
  float a0 = 0.f, a1 = 0.f;
  #pragma unroll 16
  for (int f = 0; f < 128; f += 2){
    a0 += hr[f]     * wp[f * 16];
    a1 += hr[f + 1] * wp[f * 16 + 16];
  }
  float acc = a0 + a1;
  acc += __shfl_xor(acc, 16, 64);             // reduce over kq
  acc += __shfl_xor(acc, 32, 64);
  int lane = tid & 63;
  if ((lane >> 4) == 0)
    whoB[((size_t)(n >> 3) * 16 + c) * 8 + (n & 7)] = f2h(acc);
  float p1 = acc * aout[c], p2 = acc * aout[16 + c];
  #pragma unroll
  for (int d = 1; d < 16; d <<= 1){ p1 += __shfl_xor(p1, d, 64); p2 += __shfl_xor(p2, d, 64); }
  if (lane == 0){
    r1o[n]    = __expf(-0.8f * p1);
    e21oh[n]  = f2h(__expf(p2));
    e202oh[n] = f2h(__expf(0.2f * p2));
  }
}

// ===== K4: layer-2 attention (16-way split, f16, global-direct) ============
__global__ __launch_bounds__(256) void k_att2(const u16* __restrict__ whoB,
                                              const u64* __restrict__ bits_t,
                                              const float* __restrict__ r1o,
                                              const u16* __restrict__ e21oh, const u16* __restrict__ e202oh,
                                              float* __restrict__ pnum, float* __restrict__ pden){
  __shared__ u32 smLut[4];
  int iblk  = blockIdx.x;
  int split = blockIdx.y;                     // 0..15
  int lane = threadIdx.x & 63;
  int wv   = threadIdx.x >> 6;
  int row16 = lane & 15, grp = lane >> 4;
  if (threadIdx.x < 4)
    smLut[threadIdx.x] = ((threadIdx.x & 1) ? 0xFFFFu : 0u) | ((threadIdx.x & 2) ? 0xFFFF0000u : 0u);
  __syncthreads();
  int i = iblk * 64 + wv * 16 + row16;
  u32 rb = (u32)f2h(r1o[i]); rb |= rb << 16;
  h2 rr = u2h2(rb);
  int jbeg = split * 256;
  half8 bden;
  {
    u32 z[4] = {0,0,0,0};
    if (row16 == 0){ z[0]=0x3C003C00u; z[1]=0x3C003C00u; z[2]=0x3C003C00u; z[3]=0x3C003C00u; }
    bden = pk2h8(*(uint4*)z);
  }

  f32x4 acc = {};
  f32x4 accden = {};
  #pragma unroll
  for (int c = 0; c < 4; ++c){
    int j0 = jbeg + c * 64;
    u64 mrow = bits_t[(size_t)(split * 4 + c) * 4096 + i];   // coalesced
    #pragma unroll
    for (int ks = 0; ks < 2; ++ks){
      int sb = (j0 >> 3) + ks * 4 + grp;
      half8 bf = *(const half8*)(whoB + ((size_t)sb * 16 + row16) * 8);
      uint4 e1q = *(const uint4*)(e21oh  + j0 + ks * 32 + grp * 8);
      uint4 e2q = *(const uint4*)(e202oh + j0 + ks * 32 + grp * 8);
      u32 es[4] = {e1q.x, e1q.y, e1q.z, e1q.w};
      u32 gs[4] = {e2q.x, e2q.y, e2q.z, e2q.w};
      u32 mb = ((u32)(mrow >> (ks * 32)) >> (grp * 8)) & 0xffu;
      u32 pk[4];
      #pragma unroll
      for (int t2i = 0; t2i < 4; ++t2i){
        h2 w = __builtin_elementwise_max(u2h2(es[t2i]), rr * u2h2(gs[t2i]));
        pk[t2i] = h22u(w) & smLut[(mb >> (2 * t2i)) & 3u];
      }
      half8 af = pk2h8(*(uint4*)pk);
      acc    = __builtin_amdgcn_mfma_f32_16x16x32_f16(af, bf, acc, 0, 0, 0);
      accden = __builtin_amdgcn_mfma_f32_16x16x32_f16(af, bden, accden, 0, 0, 0);
    }
  }
  #pragma unroll
  for (int r4 = 0; r4 < 4; ++r4){
    int n = iblk * 64 + wv * 16 + grp * 4 + r4;
    if (row16 == 0)
      pden[(size_t)n * 16 + split] = accden[r4];
    pnum[((size_t)n * 16 + split) * 16 + row16] = acc[r4];
  }
}

// ===== K5: combine + elu + log_softmax =====================================
__global__ __launch_bounds__(256) void k_final(const float* __restrict__ pnum,
                                               const float* __restrict__ pden,
                                               float* __restrict__ out){
  int tid = blockIdx.x * 256 + threadIdx.x;   // 65536
  int c = tid & 15;
  int n = tid >> 4;
  float num = 0.f, den = 0.f;
  #pragma unroll
  for (int s = 0; s < 16; ++s){
    num += pnum[((size_t)n * 16 + s) * 16 + c];
    den += pden[(size_t)n * 16 + s];
  }
  float v = num / den;
  v = v > 0.f ? v : (__expf(v) - 1.f);
  float m = v;
  #pragma unroll
  for (int d = 1; d < 16; d <<= 1) m = fmaxf(m, __shfl_xor(m, d, 64));
  float es = __expf(v - m), ss = es;
  #pragma unroll
  for (int d = 1; d < 16; d <<= 1) ss += __shfl_xor(ss, d, 64);
  out[(size_t)n * 16 + c] = v - m - __logf(ss);
}

// ---------------------------------------------------------------------------
extern "C" void kernel_launch(void* const* d_in, const int* in_sizes, int n_in,
                              void* d_out, int out_size, void* d_ws, size_t ws_size,
                              hipStream_t stream){
  (void)in_sizes; (void)n_in; (void)out_size; (void)ws_size;
  const float* x    = (const float*)d_in[0];
  const int*   adj  = (const int*)d_in[1];
  const float* W    = (const float*)d_in[2];
  const float* av   = (const float*)d_in[3];
  const float* Wout = (const float*)d_in[4];
  const float* aout = (const float*)d_in[5];
  float* out = (float*)d_out;
  char* ws = (char*)d_ws;

  u64*  bits_t  = (u64*)(ws + 0x0000000);        // 2 MB [64][4096]
  u16*  whB     = (u16*)(ws + 0x0200000);        // 4 MB f16 [8][j/8][o][8]
  float* r1     = (float*)(ws + 0x0600000);      // 128 KB
  u16*  e21h    = (u16*)(ws + 0x0620000);        // 64 KB f16
  u16*  e202h   = (u16*)(ws + 0x0630000);        // 64 KB f16
  u16*  pnum1   = (u16*)(ws + 0x0680000);        // 16 MB f16 [4][4096][512]
  float* pden1  = (float*)(ws + 0x1680000);      // 512 KB [4][8][4096]
  u16*  whoB    = (u16*)(ws + 0x1700000);        // 128 KB f16
  float* r1o    = (float*)(ws + 0x1720000);      // 16 KB
  u16*  e21oh   = (u16*)(ws + 0x1724000);        // 8 KB f16
  u16*  e202oh  = (u16*)(ws + 0x1726000);        // 8 KB f16
  float* pnum2  = (float*)(ws + 0x1730000);      // 4 MB [4096][16][16]
  float* pden2  = (float*)(ws + 0x1B30000);      // 256 KB
  // Wb16 aliases pnum2's region: written by k_wpack, consumed by k_gemm1,
  // then dead before k_att2 overwrites the region (stream-ordered safe).
  u16*  Wb16    = (u16*)(ws + 0x1730000);        // 512 KB f16 [8][64][64][8]

  k_wpack<<<dim3(128), dim3(256), 0, stream>>>(W, Wb16);
  k_gemm1<<<dim3(128, 8), dim3(256), 0, stream>>>(x, Wb16, av, adj, whB, bits_t, r1, e21h, e202h);
  k_att1<<<dim3(64, 8, 4), dim3(256), 0, stream>>>(whB, bits_t, r1, e21h, e202h, pnum1, pden1);
  k_gemm2<<<dim3(1024), dim3(256), 0, stream>>>(pnum1, pden1, Wout, aout, whoB, r1o, e21oh, e202oh);
  k_att2<<<dim3(64, 16), dim3(256), 0, stream>>>(whoB, bits_t, r1o, e21oh, e202oh, pnum2, pden2);
  k_final<<<dim3(256), dim3(256), 0, stream>>>(pnum2, pden2, out);
}